// Round 3
// baseline (40241.183 us; speedup 1.0000x reference)
//
#include <hip/hip_runtime.h>
#include <hip/hip_bf16.h>
#include <math.h>

#define B_  32
#define T_  800
#define L_  60
#define H_  512
#define D_  1024
#define A_  512
#define FC_ 16
#define K_  101
#define C_  4000
#define TT_ 64
#define KC_ 1536   // D_ + H_
#define NB_ 512    // persistent grid size (2 blocks/CU guaranteed co-resident)

__device__ __forceinline__ float fast_tanh(float x) {
  x = fminf(15.f, fmaxf(-15.f, x));
  float e = __expf(2.f * x);
  return (e - 1.f) / (e + 1.f);
}
__device__ __forceinline__ float fast_sig(float x) {
  return 1.f / (1.f + __expf(-x));
}
__device__ __forceinline__ float bflo(unsigned int u) {
  union { unsigned int i; float f; } v; v.i = u << 16; return v.f;
}
__device__ __forceinline__ float bfhi(unsigned int u) {
  union { unsigned int i; float f; } v; v.i = u & 0xffff0000u; return v.f;
}
__device__ __forceinline__ unsigned short f2bf(float f) {
  union { float f; unsigned int i; } v; v.f = f;
  unsigned int r = v.i + 0x7fff + ((v.i >> 16) & 1);
  return (unsigned short)(r >> 16);
}

// Device-scope grid barrier (generation counter). All NB_ blocks co-resident
// by capacity: 256 thr (<=2048/CU for 2 blocks), LDS<=80KB, VGPR<=256 via
// __launch_bounds__(256,2). __threadfence = agent fence (cross-XCD wbl2/inv).
__device__ __forceinline__ void gbar(int* cnt, int* gen) {
  __threadfence();
  __syncthreads();
  if (threadIdx.x == 0) {
    int g0 = __hip_atomic_load(gen, __ATOMIC_RELAXED, __HIP_MEMORY_SCOPE_AGENT);
    int v = __hip_atomic_fetch_add(cnt, 1, __ATOMIC_ACQ_REL, __HIP_MEMORY_SCOPE_AGENT);
    if (v == NB_ - 1) {
      __hip_atomic_store(cnt, 0, __ATOMIC_RELAXED, __HIP_MEMORY_SCOPE_AGENT);
      __hip_atomic_fetch_add(gen, 1, __ATOMIC_RELEASE, __HIP_MEMORY_SCOPE_AGENT);
    } else {
      while (__hip_atomic_load(gen, __ATOMIC_RELAXED, __HIP_MEMORY_SCOPE_AGENT) == g0) {
        __builtin_amdgcn_s_sleep(1);
      }
    }
  }
  __syncthreads();
  __threadfence();
}

// ---------------------------------------------------------------------------
// fp32 NT GEMM (precompute): O[m,n] = sum_k X[m,k]*W[n,k]; optional bf16 out.
// ---------------------------------------------------------------------------
__global__ __launch_bounds__(256) void gemm_nt_f32(
    const float* __restrict__ X, const float* __restrict__ W,
    float* __restrict__ O, unsigned short* __restrict__ Obf,
    int M, int N, int K)
{
  __shared__ float sA[16 * 132];
  __shared__ float sB[16 * 68];
  const int tid = threadIdx.x;
  const int mt = blockIdx.y * 128;
  const int nt = blockIdx.x * 64;
  const int my = tid >> 4;
  const int nx = tid & 15;
  float acc[8][4];
#pragma unroll
  for (int i = 0; i < 8; i++)
#pragma unroll
    for (int j = 0; j < 4; j++) acc[i][j] = 0.f;

  for (int k0 = 0; k0 < K; k0 += 16) {
#pragma unroll
    for (int p = 0; p < 8; p++) {
      int idx = tid + 256 * p;
      int k = idx & 15, r = idx >> 4;
      sA[k * 132 + r] = X[(size_t)(mt + r) * K + (k0 + k)];
    }
#pragma unroll
    for (int p = 0; p < 4; p++) {
      int idx = tid + 256 * p;
      int k = idx & 15, r = idx >> 4;
      sB[k * 68 + r] = W[(size_t)(nt + r) * K + (k0 + k)];
    }
    __syncthreads();
#pragma unroll
    for (int kk = 0; kk < 16; kk++) {
      float4 a0 = *(const float4*)&sA[kk * 132 + my * 8];
      float4 a1 = *(const float4*)&sA[kk * 132 + my * 8 + 4];
      float4 b0 = *(const float4*)&sB[kk * 68 + nx * 4];
      float av[8] = {a0.x, a0.y, a0.z, a0.w, a1.x, a1.y, a1.z, a1.w};
      float bv[4] = {b0.x, b0.y, b0.z, b0.w};
#pragma unroll
      for (int i = 0; i < 8; i++)
#pragma unroll
        for (int j = 0; j < 4; j++) acc[i][j] = fmaf(av[i], bv[j], acc[i][j]);
    }
    __syncthreads();
  }
  if (Obf) {
#pragma unroll
    for (int i = 0; i < 8; i++) {
      ushort4 o;
      o.x = f2bf(acc[i][0]); o.y = f2bf(acc[i][1]);
      o.z = f2bf(acc[i][2]); o.w = f2bf(acc[i][3]);
      *(ushort4*)&Obf[(size_t)(mt + my * 8 + i) * N + nt + nx * 4] = o;
    }
  } else {
#pragma unroll
    for (int i = 0; i < 8; i++) {
      float4 v = make_float4(acc[i][0], acc[i][1], acc[i][2], acc[i][3]);
      *(float4*)&O[(size_t)(mt + my * 8 + i) * N + nt + nx * 4] = v;
    }
  }
}

__global__ __launch_bounds__(256) void k_cvt_f4(
    const float4* __restrict__ in, ushort4* __restrict__ out, int n4)
{
  int i = blockIdx.x * 256 + threadIdx.x;
  if (i < n4) {
    float4 v = in[i];
    ushort4 o;
    o.x = f2bf(v.x); o.y = f2bf(v.y); o.z = f2bf(v.z); o.w = f2bf(v.w);
    out[i] = o;
  }
}

__global__ __launch_bounds__(256) void k_build_wcell(
    const float* __restrict__ W_gy, const float* __restrict__ W_sy,
    const float* __restrict__ W_gs, const float* __restrict__ W_ss,
    unsigned short* __restrict__ Wc)
{
  int idx = blockIdx.x * 256 + threadIdx.x;
  if (idx >= 5 * H_ * KC_) return;
  int row = idx / KC_;
  int k = idx - row * KC_;
  int gt = row >> 9, h = row & (H_ - 1);
  float v;
  if (gt == 0)
    v = (k < D_) ? W_gy[(size_t)h * D_ + k] : W_sy[(size_t)h * H_ + (k - D_)];
  else {
    int r = (gt - 1) * H_ + h;
    v = (k < D_) ? W_gs[(size_t)r * D_ + k] : W_ss[(size_t)r * H_ + (k - D_)];
  }
  Wc[idx] = f2bf(v);
}

// ---------------------------------------------------------------------------
// Persistent decode loop: all 60 steps, 5 phases/step, grid barriers between.
// LDS: persistent (W_fe^T 32K + conv_w 6.3K) + phase union 24.7K = 63.9 KB.
// ---------------------------------------------------------------------------
__global__ __launch_bounds__(256, 2) void k_decode(
    const unsigned short* __restrict__ hEbf,
    const unsigned short* __restrict__ hbbf,
    const unsigned short* __restrict__ Wcell,
    const unsigned short* __restrict__ Wyybf,
    const float* __restrict__ TY,
    const float* __restrict__ W_fe, const float* __restrict__ conv_w,
    const float* __restrict__ conv_b, const float* __restrict__ w_ee,
    const float* __restrict__ W_se,
    const float* __restrict__ b_gy, const float* __restrict__ b_gs,
    const float* __restrict__ b_yy,
    const int* __restrict__ lengths,
    float* __restrict__ alpha, float* __restrict__ e,
    float* __restrict__ g, float* __restrict__ part,
    float* __restrict__ s0buf, float* __restrict__ s1buf,
    float* __restrict__ c, float* __restrict__ u,
    float* __restrict__ sE, float* __restrict__ out,
    int* __restrict__ bar)
{
  __shared__ float s_wfeT[FC_ * A_];   // persistent: W_fe transposed [f][a]
  __shared__ float s_cw[FC_ * K_];     // persistent: conv weights
  __shared__ union {
    struct { float wee[A_]; float sE[A_]; float al[TT_ + K_ - 1]; float cf[TT_ * FC_]; } att;
    struct { float red[256]; float ash[256]; } sm;
    struct { float sx[32 * 193]; } cell;
    struct { float sv[H_]; } outp;
  } ph;

  const int bk = blockIdx.x;
  const int tid = threadIdx.x;

  for (int i = tid; i < FC_ * A_; i += 256) {
    int f = i >> 9, a = i & (A_ - 1);
    s_wfeT[i] = W_fe[a * FC_ + f];
  }
  for (int i = tid; i < FC_ * K_; i += 256) s_cw[i] = conv_w[i];
  __syncthreads();

  for (int l = 0; l < L_; l++) {
    const float* s_in = (l & 1) ? s1buf : s0buf;
    float* s_out = (l & 1) ? s0buf : s1buf;

    // ---------------- phase 1: attention energies e[b,t] ----------------
    {
      const int b = bk & 31;
      const int tc = bk >> 5;                 // 0..15; active if tc < 13
      if (tc < 13) {
        const int t0 = tc * TT_;
        const int len = lengths[b];
        if (t0 < len) {
          for (int idx = tid; idx < TT_ + K_ - 1; idx += 256) {
            int t = t0 - (K_ / 2) + idx;
            ph.att.al[idx] = (t >= 0 && t < T_) ? alpha[b * T_ + t] : 0.f;
          }
          for (int idx = tid; idx < A_; idx += 256) {
            ph.att.sE[idx] = sE[b * A_ + idx];
            ph.att.wee[idx] = w_ee[idx];
          }
          __syncthreads();
          for (int idx = tid; idx < TT_ * FC_; idx += 256) {
            int tl = idx >> 4, f = idx & 15;
            float acc2 = conv_b[f];
            for (int k = 0; k < K_; k++)
              acc2 = fmaf(ph.att.al[tl + k], s_cw[f * K_ + k], acc2);
            ph.att.cf[tl * FC_ + f] = acc2;
          }
          __syncthreads();
          const int wave = tid >> 6, lane = tid & 63;
          for (int tl = wave; tl < TT_; tl += 4) {
            int t = t0 + tl;
            if (t >= len) continue;
            float cf[FC_];
#pragma unroll
            for (int f = 0; f < FC_; f++) cf[f] = ph.att.cf[tl * FC_ + f];
            const unsigned short* hEp = hEbf + ((size_t)(b * T_ + t)) * A_;
            float pt = 0.f;
#pragma unroll
            for (int j = 0; j < 4; j++) {
              int a0 = j * 128 + lane * 2;
              float F0 = 0.f, F1 = 0.f;
#pragma unroll
              for (int f = 0; f < FC_; f++) {
                float2 wf = *(const float2*)&s_wfeT[f * A_ + a0];
                F0 = fmaf(wf.x, cf[f], F0);
                F1 = fmaf(wf.y, cf[f], F1);
              }
              unsigned int hp = *(const unsigned int*)&hEp[a0];
              float v0 = fast_tanh(ph.att.sE[a0] + bflo(hp) + F0);
              float v1 = fast_tanh(ph.att.sE[a0 + 1] + bfhi(hp) + F1);
              pt = fmaf(ph.att.wee[a0], v0, pt);
              pt = fmaf(ph.att.wee[a0 + 1], v1, pt);
            }
#pragma unroll
            for (int off = 32; off > 0; off >>= 1) pt += __shfl_down(pt, off);
            if (lane == 0) e[b * T_ + t] = pt;
          }
        }
      }
    }
    gbar(bar, bar + 1);

    // ---------------- phase 2: softmax + g (d-chunk = 64) ----------------
    {
      const int b = bk >> 4;
      const int d0 = (bk & 15) * 64;
      const int len = lengths[b];
      float m = -3.0e38f;
      for (int t = tid; t < len; t += 256) m = fmaxf(m, e[b * T_ + t]);
      ph.sm.red[tid] = m;
      __syncthreads();
      for (int s2 = 128; s2 > 0; s2 >>= 1) {
        if (tid < s2) ph.sm.red[tid] = fmaxf(ph.sm.red[tid], ph.sm.red[tid + s2]);
        __syncthreads();
      }
      m = ph.sm.red[0];
      __syncthreads();
      float zs = 0.f;
      for (int t = tid; t < len; t += 256) zs += __expf(e[b * T_ + t] - m);
      ph.sm.red[tid] = zs;
      __syncthreads();
      for (int s2 = 128; s2 > 0; s2 >>= 1) {
        if (tid < s2) ph.sm.red[tid] += ph.sm.red[tid + s2];
        __syncthreads();
      }
      const float invZ = 1.f / ph.sm.red[0];
      __syncthreads();

      const int dloc = tid & 63, tph = tid >> 6;
      float gacc = 0.f;
      for (int tb = 0; tb < len; tb += 256) {
        int t = tb + tid;
        float av = (t < len) ? __expf(e[b * T_ + t] - m) * invZ : 0.f;
        ph.sm.ash[tid] = av;
        __syncthreads();
        if ((bk & 15) == 0 && t < len) alpha[b * T_ + t] = av;
        int cnt2 = min(256, len - tb);
        for (int tt = tph; tt < cnt2; tt += 4) {
          unsigned int us = hbbf[((size_t)(b * T_ + tb + tt)) * D_ + d0 + dloc];
          gacc = fmaf(ph.sm.ash[tt], bflo(us), gacc);
        }
        __syncthreads();
      }
      ph.sm.red[tid] = gacc;
      __syncthreads();
      if (tid < 64)
        g[b * D_ + d0 + tid] = ph.sm.red[tid] + ph.sm.red[tid + 64] +
                               ph.sm.red[tid + 128] + ph.sm.red[tid + 192];
    }
    gbar(bar, bar + 1);

    // ---------------- phase 3: cell partial dots (split-K x8) ----------------
    {
      const int ks = bk >> 6;
      const int xb = bk & 63;
      const int k0 = ks * 192;
      for (int i = tid; i < 32 * 192; i += 256) {
        int bb = i / 192, dd = i - bb * 192;
        int k = k0 + dd;
        ph.cell.sx[bb * 193 + dd] =
            (k < D_) ? g[bb * D_ + k] : s_in[bb * H_ + (k - D_)];
      }
      __syncthreads();
      const int gid = xb * 256 + tid;
      const int b = gid & 31, h = gid >> 5;
      const float* xp = &ph.cell.sx[b * 193];
      float acc[5] = {0.f, 0.f, 0.f, 0.f, 0.f};
      const uint4* w[5];
#pragma unroll
      for (int gt = 0; gt < 5; gt++)
        w[gt] = (const uint4*)(Wcell + ((size_t)(gt * H_ + h)) * KC_ + k0);
#pragma unroll 4
      for (int i = 0; i < 24; i++) {
        uint4 uu[5];
#pragma unroll
        for (int gt = 0; gt < 5; gt++) uu[gt] = w[gt][i];
        float xv[8];
#pragma unroll
        for (int e2 = 0; e2 < 8; e2++) xv[e2] = xp[i * 8 + e2];
#pragma unroll
        for (int gt = 0; gt < 5; gt++) {
          acc[gt] = fmaf(bflo(uu[gt].x), xv[0], acc[gt]);
          acc[gt] = fmaf(bfhi(uu[gt].x), xv[1], acc[gt]);
          acc[gt] = fmaf(bflo(uu[gt].y), xv[2], acc[gt]);
          acc[gt] = fmaf(bfhi(uu[gt].y), xv[3], acc[gt]);
          acc[gt] = fmaf(bflo(uu[gt].z), xv[4], acc[gt]);
          acc[gt] = fmaf(bfhi(uu[gt].z), xv[5], acc[gt]);
          acc[gt] = fmaf(bflo(uu[gt].w), xv[6], acc[gt]);
          acc[gt] = fmaf(bfhi(uu[gt].w), xv[7], acc[gt]);
        }
      }
#pragma unroll
      for (int gt = 0; gt < 5; gt++)
        part[(size_t)(ks * 5 + gt) * 16384 + gid] = acc[gt];
      __syncthreads();
    }
    gbar(bar, bar + 1);

    // ---------------- phase 4: reduce + activations + state ----------------
    if (bk < 64) {
      const int gid = bk * 256 + tid;
      const int b = gid & 31, h = gid >> 5;
      float s[5] = {0.f, 0.f, 0.f, 0.f, 0.f};
#pragma unroll
      for (int ks = 0; ks < 8; ks++)
#pragma unroll
        for (int gt = 0; gt < 5; gt++)
          s[gt] += part[(size_t)(ks * 5 + gt) * 16384 + gid];
      const float* ty = TY + ((size_t)b * L_ + l) * (4 * H_);
      float uv = fast_tanh(s[0] + b_gy[h]);
      float iv = s[1] + ty[h] + b_gs[h];
      float fv = s[2] + ty[h + H_] + b_gs[h + H_];
      float cg = s[3] + ty[h + 2 * H_] + b_gs[h + 2 * H_];
      float ov = s[4] + ty[h + 3 * H_] + b_gs[h + 3 * H_];
      float cn = fast_sig(fv) * c[b * H_ + h] + fast_sig(iv) * fast_tanh(cg);
      c[b * H_ + h] = cn;
      s_out[b * H_ + h] = fast_sig(ov) * fast_tanh(cn);
      u[b * H_ + h] = uv;
    }
    gbar(bar, bar + 1);

    // ---------------- phase 5: y output + sE projection ----------------
    for (int uo = bk; uo < 576; uo += NB_) {
      const int b = uo / 18;
      const int x = uo - b * 18;
      if (x < 16) {
        for (int i = tid; i < H_; i += 256) ph.outp.sv[i] = u[b * H_ + i];
        __syncthreads();
        int cc = x * 256 + tid;
        if (cc < C_) {
          const uint4* row = (const uint4*)(Wyybf + (size_t)cc * H_);
          float acc = b_yy[cc];
#pragma unroll 8
          for (int i = 0; i < 64; i++) {
            uint4 ww = row[i];
            const float* xp = &ph.outp.sv[i * 8];
            acc = fmaf(bflo(ww.x), xp[0], acc);
            acc = fmaf(bfhi(ww.x), xp[1], acc);
            acc = fmaf(bflo(ww.y), xp[2], acc);
            acc = fmaf(bfhi(ww.y), xp[3], acc);
            acc = fmaf(bflo(ww.z), xp[4], acc);
            acc = fmaf(bfhi(ww.z), xp[5], acc);
            acc = fmaf(bflo(ww.w), xp[6], acc);
            acc = fmaf(bfhi(ww.w), xp[7], acc);
          }
          out[((size_t)b * L_ + l) * C_ + cc] = acc;
        }
        __syncthreads();
      } else {
        for (int i = tid; i < H_; i += 256) ph.outp.sv[i] = s_out[b * H_ + i];
        __syncthreads();
        int a = (x - 16) * 256 + tid;
        const float4* row = (const float4*)(W_se + (size_t)a * H_);
        float acc = 0.f;
#pragma unroll 8
        for (int i = 0; i < 128; i++) {
          float4 ww = row[i];
          const float* xp = &ph.outp.sv[i * 4];
          acc = fmaf(ww.x, xp[0], acc);
          acc = fmaf(ww.y, xp[1], acc);
          acc = fmaf(ww.z, xp[2], acc);
          acc = fmaf(ww.w, xp[3], acc);
        }
        sE[b * A_ + a] = acc;
        __syncthreads();
      }
    }
    gbar(bar, bar + 1);
  }
}

// ---------------------------------------------------------------------------
extern "C" void kernel_launch(void* const* d_in, const int* in_sizes, int n_in,
                              void* d_out, int out_size, void* d_ws, size_t ws_size,
                              hipStream_t stream)
{
  const float* hbatch  = (const float*)d_in[0];
  const int*   lengths = (const int*)d_in[1];
  const float* targets = (const float*)d_in[2];
  const float* W_sy = (const float*)d_in[3];
  const float* W_gy = (const float*)d_in[4];
  const float* b_gy = (const float*)d_in[5];
  const float* W_yy = (const float*)d_in[6];
  const float* b_yy = (const float*)d_in[7];
  const float* W_ys = (const float*)d_in[8];
  const float* W_ss = (const float*)d_in[9];
  const float* W_gs = (const float*)d_in[10];
  const float* b_gs = (const float*)d_in[11];
  const float* W_se = (const float*)d_in[12];
  const float* W_he = (const float*)d_in[13];
  const float* W_fe = (const float*)d_in[14];
  const float* conv_w = (const float*)d_in[15];
  const float* conv_b = (const float*)d_in[16];
  const float* w_ee   = (const float*)d_in[17];
  float* out = (float*)d_out;

  char* ws = (char*)d_ws;
  size_t off = 0;
  auto alloc = [&](size_t bytes) -> void* {
    void* p = ws + off;
    off += (bytes + 255) & ~(size_t)255;
    return p;
  };
  unsigned short* hEbf  = (unsigned short*)alloc((size_t)B_ * T_ * A_ * 2);
  unsigned short* hbbf  = (unsigned short*)alloc((size_t)B_ * T_ * D_ * 2);
  unsigned short* Wcell = (unsigned short*)alloc((size_t)5 * H_ * KC_ * 2);
  unsigned short* Wyybf = (unsigned short*)alloc((size_t)C_ * H_ * 2);
  float* TY    = (float*)alloc((size_t)B_ * L_ * 4 * H_ * 4);
  float* part  = (float*)alloc((size_t)8 * 5 * 16384 * 4);
  float* alpha = (float*)alloc((size_t)B_ * T_ * 4);
  float* e     = (float*)alloc((size_t)B_ * T_ * 4);
  float* g     = (float*)alloc((size_t)B_ * D_ * 4);
  float* s0    = (float*)alloc((size_t)B_ * H_ * 4);
  float* s1    = (float*)alloc((size_t)B_ * H_ * 4);
  float* c     = (float*)alloc((size_t)B_ * H_ * 4);
  float* u     = (float*)alloc((size_t)B_ * H_ * 4);
  float* sE    = (float*)alloc((size_t)B_ * A_ * 4);
  int*   bar   = (int*)alloc(2 * sizeof(int));

  hipMemsetAsync(alpha, 0, (size_t)B_ * T_ * 4, stream);
  hipMemsetAsync(s0, 0, (size_t)B_ * H_ * 4, stream);
  hipMemsetAsync(c, 0, (size_t)B_ * H_ * 4, stream);
  hipMemsetAsync(sE, 0, (size_t)B_ * A_ * 4, stream);
  hipMemsetAsync(bar, 0, 2 * sizeof(int), stream);

  // ---- precompute ----
  {
    int n4 = B_ * T_ * D_ / 4;
    k_cvt_f4<<<(n4 + 255) / 256, 256, 0, stream>>>((const float4*)hbatch,
                                                   (ushort4*)hbbf, n4);
    int n4y = C_ * H_ / 4;
    k_cvt_f4<<<(n4y + 255) / 256, 256, 0, stream>>>((const float4*)W_yy,
                                                    (ushort4*)Wyybf, n4y);
    int nw = 5 * H_ * KC_;
    k_build_wcell<<<(nw + 255) / 256, 256, 0, stream>>>(W_gy, W_sy, W_gs, W_ss,
                                                        Wcell);
    gemm_nt_f32<<<dim3(A_ / 64, (B_ * T_) / 128), 256, 0, stream>>>(
        hbatch, W_he, nullptr, hEbf, B_ * T_, A_, D_);
    gemm_nt_f32<<<dim3((4 * H_) / 64, (B_ * L_) / 128), 256, 0, stream>>>(
        targets, W_ys, TY, nullptr, B_ * L_, 4 * H_, C_);
  }

  // ---- persistent 60-step decode loop ----
  k_decode<<<NB_, 256, 0, stream>>>(
      hEbf, hbbf, Wcell, Wyybf, TY, W_fe, conv_w, conv_b, w_ee, W_se,
      b_gy, b_gs, b_yy, lengths, alpha, e, g, part, s0, s1, c, u, sE, out, bar);
}

// Round 4
// 8663.816 us; speedup vs baseline: 4.6447x; 4.6447x over previous
//
#include <hip/hip_runtime.h>
#include <hip/hip_bf16.h>
#include <math.h>

#define B_  32
#define T_  800
#define L_  60
#define H_  512
#define D_  1024
#define A_  512
#define FC_ 16
#define K_  101
#define C_  4000
#define TT_ 64
#define KC_ 1536   // D_ + H_

typedef short bf16x8 __attribute__((ext_vector_type(8)));
typedef float f32x4 __attribute__((ext_vector_type(4)));

__device__ __forceinline__ float fast_tanh(float x) {
  x = fminf(15.f, fmaxf(-15.f, x));
  float e = __expf(2.f * x);
  return (e - 1.f) / (e + 1.f);
}
__device__ __forceinline__ float fast_sig(float x) {
  return 1.f / (1.f + __expf(-x));
}
__device__ __forceinline__ float bflo(unsigned int u) {
  union { unsigned int i; float f; } v; v.i = u << 16; return v.f;
}
__device__ __forceinline__ float bfhi(unsigned int u) {
  union { unsigned int i; float f; } v; v.i = u & 0xffff0000u; return v.f;
}
__device__ __forceinline__ unsigned short f2bf(float f) {
  union { float f; unsigned int i; } v; v.f = f;
  unsigned int r = v.i + 0x7fff + ((v.i >> 16) & 1);
  return (unsigned short)(r >> 16);
}

// ---------------------------------------------------------------------------
// bf16 MFMA NT GEMM: C[m,n] = sum_k A[m,k]*B[n,k] (+bias[n]).
// 128x128 tile, BK=32, 256 thr (4 waves, 2x2 of 64x64), 16x16x32 MFMA.
// M%128==0, K%32==0; N guarded. Output fp32 (O) or bf16 (Obf).
// ---------------------------------------------------------------------------
__global__ __launch_bounds__(256) void gemm_bf16_nt(
    const unsigned short* __restrict__ Am, const unsigned short* __restrict__ Bm,
    float* __restrict__ O, unsigned short* __restrict__ Obf,
    const float* __restrict__ bias, int M, int N, int K)
{
  __shared__ unsigned short sA[128 * 40];   // stride 40 -> bank-safe
  __shared__ unsigned short sB[128 * 40];
  const int tid = threadIdx.x;
  const int mt = blockIdx.y * 128, nt = blockIdx.x * 128;
  const int wave = tid >> 6, lane = tid & 63;
  const int wm = (wave & 1) * 64, wn = (wave >> 1) * 64;
  const int qd = lane >> 4, md = lane & 15;

  f32x4 acc[4][4];
#pragma unroll
  for (int i = 0; i < 4; i++)
#pragma unroll
    for (int j = 0; j < 4; j++) acc[i][j] = (f32x4){0.f, 0.f, 0.f, 0.f};

  for (int k0 = 0; k0 < K; k0 += 32) {
#pragma unroll
    for (int p = 0; p < 2; p++) {
      int idx = tid + p * 256;            // 0..511
      int r = idx >> 2, kq = (idx & 3) * 8;
      *(uint4*)&sA[r * 40 + kq] =
          *(const uint4*)&Am[(size_t)(mt + r) * K + k0 + kq];
      uint4 bv = make_uint4(0, 0, 0, 0);
      if (nt + r < N) bv = *(const uint4*)&Bm[(size_t)(nt + r) * K + k0 + kq];
      *(uint4*)&sB[r * 40 + kq] = bv;
    }
    __syncthreads();
    bf16x8 af[4], bfr[4];
#pragma unroll
    for (int i = 0; i < 4; i++) {
      af[i]  = *(const bf16x8*)&sA[(wm + i * 16 + md) * 40 + qd * 8];
      bfr[i] = *(const bf16x8*)&sB[(wn + i * 16 + md) * 40 + qd * 8];
    }
#pragma unroll
    for (int mi = 0; mi < 4; mi++)
#pragma unroll
      for (int ni = 0; ni < 4; ni++)
        acc[mi][ni] = __builtin_amdgcn_mfma_f32_16x16x32_bf16(
            af[mi], bfr[ni], acc[mi][ni], 0, 0, 0);
    __syncthreads();
  }

#pragma unroll
  for (int mi = 0; mi < 4; mi++)
#pragma unroll
    for (int ni = 0; ni < 4; ni++) {
      int gn = nt + wn + ni * 16 + md;
      if (gn >= N) continue;
      float bv = bias ? bias[gn] : 0.f;
#pragma unroll
      for (int reg = 0; reg < 4; reg++) {
        int gm = mt + wm + mi * 16 + qd * 4 + reg;
        float v = acc[mi][ni][reg] + bv;
        if (Obf) Obf[(size_t)gm * N + gn] = f2bf(v);
        else     O[(size_t)gm * N + gn] = v;
      }
    }
}

// ---------------------------------------------------------------------------
__global__ __launch_bounds__(256) void k_cvt_f4(
    const float4* __restrict__ in, ushort4* __restrict__ out, int n4)
{
  int i = blockIdx.x * 256 + threadIdx.x;
  if (i < n4) {
    float4 v = in[i];
    ushort4 o;
    o.x = f2bf(v.x); o.y = f2bf(v.y); o.z = f2bf(v.z); o.w = f2bf(v.w);
    out[i] = o;
  }
}

// Wcell[gate][h][k], gate 0=U(W_gy|W_sy), 1..4 = I,F,Cg,O (W_gs|W_ss)
__global__ __launch_bounds__(256) void k_build_wcell(
    const float* __restrict__ W_gy, const float* __restrict__ W_sy,
    const float* __restrict__ W_gs, const float* __restrict__ W_ss,
    unsigned short* __restrict__ Wc)
{
  int idx = blockIdx.x * 256 + threadIdx.x;
  if (idx >= 5 * H_ * KC_) return;
  int row = idx / KC_;
  int k = idx - row * KC_;
  int gt = row >> 9, h = row & (H_ - 1);
  float v;
  if (gt == 0)
    v = (k < D_) ? W_gy[(size_t)h * D_ + k] : W_sy[(size_t)h * H_ + (k - D_)];
  else {
    int r = (gt - 1) * H_ + h;
    v = (k < D_) ? W_gs[(size_t)r * D_ + k] : W_ss[(size_t)r * H_ + (k - D_)];
  }
  Wc[idx] = f2bf(v);
}

// ---------------------------------------------------------------------------
// Fused conv(alpha) + W_fe proj + tanh energy + w_ee dot. hE is bf16.
// grid (13, B), 256 threads.
// ---------------------------------------------------------------------------
__global__ __launch_bounds__(256) void k_att(
    const float* __restrict__ alpha, const float* __restrict__ sE,
    const unsigned short* __restrict__ hEbf, const float* __restrict__ conv_w,
    const float* __restrict__ conv_b, const float* __restrict__ W_fe,
    const float* __restrict__ w_ee, const int* __restrict__ lengths,
    float* __restrict__ e)
{
  const int b = blockIdx.y;
  const int t0 = blockIdx.x * TT_;
  const int len = lengths[b];
  if (t0 >= len) return;

  __shared__ float s_alpha[TT_ + K_ - 1];
  __shared__ float s_cf[TT_ * FC_];
  __shared__ float s_sE[A_];
  __shared__ float s_wee[A_];
  __shared__ float s_wfeT[FC_ * A_];
  __shared__ float s_cw[FC_ * K_];

  const int tid = threadIdx.x;
  for (int idx = tid; idx < TT_ + K_ - 1; idx += 256) {
    int t = t0 - (K_ / 2) + idx;
    s_alpha[idx] = (t >= 0 && t < T_) ? alpha[b * T_ + t] : 0.f;
  }
  for (int idx = tid; idx < A_; idx += 256) {
    s_sE[idx] = sE[b * A_ + idx];
    s_wee[idx] = w_ee[idx];
  }
  for (int idx = tid; idx < FC_ * A_; idx += 256) {
    int f = idx >> 9, a = idx & (A_ - 1);
    s_wfeT[idx] = W_fe[a * FC_ + f];
  }
  for (int idx = tid; idx < FC_ * K_; idx += 256) s_cw[idx] = conv_w[idx];
  __syncthreads();

  for (int idx = tid; idx < TT_ * FC_; idx += 256) {
    int tl = idx >> 4, f = idx & 15;
    float acc2 = conv_b[f];
    for (int k = 0; k < K_; k++) acc2 = fmaf(s_alpha[tl + k], s_cw[f * K_ + k], acc2);
    s_cf[tl * FC_ + f] = acc2;
  }
  __syncthreads();

  const int wave = tid >> 6, lane = tid & 63;
  for (int tl = wave; tl < TT_; tl += 4) {
    int t = t0 + tl;
    if (t >= len) continue;
    float cf[FC_];
#pragma unroll
    for (int f = 0; f < FC_; f++) cf[f] = s_cf[tl * FC_ + f];
    const unsigned short* hEp = hEbf + ((size_t)(b * T_ + t)) * A_;
    float pt = 0.f;
#pragma unroll
    for (int j = 0; j < 4; j++) {
      int a0 = j * 128 + lane * 2;
      float F0 = 0.f, F1 = 0.f;
#pragma unroll
      for (int f = 0; f < FC_; f++) {
        float2 wf = *(const float2*)&s_wfeT[f * A_ + a0];
        F0 = fmaf(wf.x, cf[f], F0);
        F1 = fmaf(wf.y, cf[f], F1);
      }
      unsigned int hp = *(const unsigned int*)&hEp[a0];
      float v0 = fast_tanh(s_sE[a0] + bflo(hp) + F0);
      float v1 = fast_tanh(s_sE[a0 + 1] + bfhi(hp) + F1);
      pt = fmaf(s_wee[a0], v0, pt);
      pt = fmaf(s_wee[a0 + 1], v1, pt);
    }
#pragma unroll
    for (int off = 32; off > 0; off >>= 1) pt += __shfl_down(pt, off);
    if (lane == 0) e[b * T_ + t] = pt;
  }
}

// ---------------------------------------------------------------------------
// Per-b softmax (redundant per d-chunk) + g = sum_t alpha*hbatch (bf16) + alpha.
// grid (8, B): d-chunk 128 (2/lane), 4-way t-split.
// ---------------------------------------------------------------------------
__global__ __launch_bounds__(256) void k_softmax_g(
    const float* __restrict__ e, const unsigned short* __restrict__ hb,
    const int* __restrict__ lengths, float* __restrict__ alpha,
    float* __restrict__ g)
{
  const int b = blockIdx.y;
  const int d0 = blockIdx.x * 128;
  const int len = lengths[b];
  const int tid = threadIdx.x;
  __shared__ float red[256];
  __shared__ float red2[256];
  __shared__ float a_sh[256];

  float m = -3.0e38f;
  for (int t = tid; t < len; t += 256) m = fmaxf(m, e[b * T_ + t]);
  red[tid] = m;
  __syncthreads();
  for (int s = 128; s > 0; s >>= 1) {
    if (tid < s) red[tid] = fmaxf(red[tid], red[tid + s]);
    __syncthreads();
  }
  m = red[0];
  __syncthreads();
  float zs = 0.f;
  for (int t = tid; t < len; t += 256) zs += __expf(e[b * T_ + t] - m);
  red[tid] = zs;
  __syncthreads();
  for (int s = 128; s > 0; s >>= 1) {
    if (tid < s) red[tid] += red[tid + s];
    __syncthreads();
  }
  const float invZ = 1.f / red[0];
  __syncthreads();

  const int dloc = (tid & 63) * 2, tph = tid >> 6;
  float g0 = 0.f, g1 = 0.f;
  for (int t0 = 0; t0 < len; t0 += 256) {
    int t = t0 + tid;
    float av = (t < len) ? __expf(e[b * T_ + t] - m) * invZ : 0.f;
    a_sh[tid] = av;
    __syncthreads();
    if (blockIdx.x == 0 && t < len) alpha[b * T_ + t] = av;
    int cnt = min(256, len - t0);
    for (int tt = tph; tt < cnt; tt += 4) {
      unsigned int hp =
          *(const unsigned int*)&hb[((size_t)(b * T_ + t0 + tt)) * D_ + d0 + dloc];
      float av2 = a_sh[tt];
      g0 = fmaf(av2, bflo(hp), g0);
      g1 = fmaf(av2, bfhi(hp), g1);
    }
    __syncthreads();
  }
  red[tid] = g0;
  red2[tid] = g1;
  __syncthreads();
  if (tid < 64) {
    float r0 = red[tid] + red[tid + 64] + red[tid + 128] + red[tid + 192];
    float r1 = red2[tid] + red2[tid + 64] + red2[tid + 128] + red2[tid + 192];
    g[b * D_ + d0 + 2 * tid]     = r0;
    g[b * D_ + d0 + 2 * tid + 1] = r1;
  }
}

// ---------------------------------------------------------------------------
// Cell partials: split-K x8. grid (64, 8). Wcell bf16 [5][512][1536].
// ---------------------------------------------------------------------------
__global__ __launch_bounds__(256) void k_cell(
    const float* __restrict__ g, const float* __restrict__ s_in,
    const unsigned short* __restrict__ Wc, float* __restrict__ part)
{
  __shared__ float sx[32 * 193];
  const int tid = threadIdx.x;
  const int ks = blockIdx.y;
  const int k0 = ks * 192;
  for (int i = tid; i < 32 * 192; i += 256) {
    int bb = i / 192, dd = i - bb * 192;
    int k = k0 + dd;
    sx[bb * 193 + dd] = (k < D_) ? g[bb * D_ + k] : s_in[bb * H_ + (k - D_)];
  }
  __syncthreads();
  const int gid = blockIdx.x * 256 + tid;
  const int b = gid & 31, h = gid >> 5;
  const float* xp = &sx[b * 193];
  float acc[5] = {0.f, 0.f, 0.f, 0.f, 0.f};
  const uint4* w[5];
#pragma unroll
  for (int gt = 0; gt < 5; gt++)
    w[gt] = (const uint4*)(Wc + ((size_t)(gt * H_ + h)) * KC_ + k0);
#pragma unroll 4
  for (int i = 0; i < 24; i++) {
    uint4 uu[5];
#pragma unroll
    for (int gt = 0; gt < 5; gt++) uu[gt] = w[gt][i];
    float xv[8];
#pragma unroll
    for (int e2 = 0; e2 < 8; e2++) xv[e2] = xp[i * 8 + e2];
#pragma unroll
    for (int gt = 0; gt < 5; gt++) {
      acc[gt] = fmaf(bflo(uu[gt].x), xv[0], acc[gt]);
      acc[gt] = fmaf(bfhi(uu[gt].x), xv[1], acc[gt]);
      acc[gt] = fmaf(bflo(uu[gt].y), xv[2], acc[gt]);
      acc[gt] = fmaf(bfhi(uu[gt].y), xv[3], acc[gt]);
      acc[gt] = fmaf(bflo(uu[gt].z), xv[4], acc[gt]);
      acc[gt] = fmaf(bfhi(uu[gt].z), xv[5], acc[gt]);
      acc[gt] = fmaf(bflo(uu[gt].w), xv[6], acc[gt]);
      acc[gt] = fmaf(bfhi(uu[gt].w), xv[7], acc[gt]);
    }
  }
#pragma unroll
  for (int gt = 0; gt < 5; gt++)
    part[(size_t)(ks * 5 + gt) * 16384 + gid] = acc[gt];
}

// ---------------------------------------------------------------------------
// Reduce partials + activations + state update + u_all(bf16) + sE projection.
// grid 32 blocks (one per b), 256 threads.
// ---------------------------------------------------------------------------
__global__ __launch_bounds__(256) void k_fin_se(
    const float* __restrict__ part, float* __restrict__ c,
    const float* __restrict__ TY, int l,
    const float* __restrict__ b_gy, const float* __restrict__ b_gs,
    const unsigned short* __restrict__ W_sebf,
    unsigned short* __restrict__ u_all, float* __restrict__ s_out,
    float* __restrict__ sE)
{
  const int b = blockIdx.x;
  const int tid = threadIdx.x;
  __shared__ float sv[H_];
  const float* ty = TY + ((size_t)b * L_ + l) * (4 * H_);

  for (int h = tid; h < H_; h += 256) {
    float s[5] = {0.f, 0.f, 0.f, 0.f, 0.f};
#pragma unroll
    for (int ks = 0; ks < 8; ks++)
#pragma unroll
      for (int gt = 0; gt < 5; gt++)
        s[gt] += part[(size_t)(ks * 5 + gt) * 16384 + h * 32 + b];
    float uv = fast_tanh(s[0] + b_gy[h]);
    float iv = s[1] + ty[h] + b_gs[h];
    float fv = s[2] + ty[h + H_] + b_gs[h + H_];
    float cg = s[3] + ty[h + 2 * H_] + b_gs[h + 2 * H_];
    float ov = s[4] + ty[h + 3 * H_] + b_gs[h + 3 * H_];
    float cn = fast_sig(fv) * c[b * H_ + h] + fast_sig(iv) * fast_tanh(cg);
    c[b * H_ + h] = cn;
    float sn = fast_sig(ov) * fast_tanh(cn);
    s_out[b * H_ + h] = sn;
    sv[h] = sn;
    u_all[((size_t)b * L_ + l) * H_ + h] = f2bf(uv);
  }
  __syncthreads();

  for (int a = tid; a < A_; a += 256) {
    const uint4* row = (const uint4*)(W_sebf + (size_t)a * H_);
    float acc = 0.f;
#pragma unroll 8
    for (int i = 0; i < 64; i++) {
      uint4 ww = row[i];
      const float* xp = &sv[i * 8];
      acc = fmaf(bflo(ww.x), xp[0], acc);
      acc = fmaf(bfhi(ww.x), xp[1], acc);
      acc = fmaf(bflo(ww.y), xp[2], acc);
      acc = fmaf(bfhi(ww.y), xp[3], acc);
      acc = fmaf(bflo(ww.z), xp[4], acc);
      acc = fmaf(bfhi(ww.z), xp[5], acc);
      acc = fmaf(bflo(ww.w), xp[6], acc);
      acc = fmaf(bfhi(ww.w), xp[7], acc);
    }
    sE[b * A_ + a] = acc;
  }
}

// ---------------------------------------------------------------------------
extern "C" void kernel_launch(void* const* d_in, const int* in_sizes, int n_in,
                              void* d_out, int out_size, void* d_ws, size_t ws_size,
                              hipStream_t stream)
{
  const float* hbatch  = (const float*)d_in[0];
  const int*   lengths = (const int*)d_in[1];
  const float* targets = (const float*)d_in[2];
  const float* W_sy = (const float*)d_in[3];
  const float* W_gy = (const float*)d_in[4];
  const float* b_gy = (const float*)d_in[5];
  const float* W_yy = (const float*)d_in[6];
  const float* b_yy = (const float*)d_in[7];
  const float* W_ys = (const float*)d_in[8];
  const float* W_ss = (const float*)d_in[9];
  const float* W_gs = (const float*)d_in[10];
  const float* b_gs = (const float*)d_in[11];
  const float* W_se = (const float*)d_in[12];
  const float* W_he = (const float*)d_in[13];
  const float* W_fe = (const float*)d_in[14];
  const float* conv_w = (const float*)d_in[15];
  const float* conv_b = (const float*)d_in[16];
  const float* w_ee   = (const float*)d_in[17];
  float* out = (float*)d_out;

  char* ws = (char*)d_ws;
  size_t off = 0;
  auto alloc = [&](size_t bytes) -> void* {
    void* p = ws + off;
    off += (bytes + 255) & ~(size_t)255;
    return p;
  };
  unsigned short* hEbf   = (unsigned short*)alloc((size_t)B_ * T_ * A_ * 2);   // 26.2 MB
  unsigned short* hbbf   = (unsigned short*)alloc((size_t)B_ * T_ * D_ * 2);   // 52.4 MB
  unsigned short* Wcell  = (unsigned short*)alloc((size_t)5 * H_ * KC_ * 2);   // 7.9 MB
  unsigned short* Wyybf  = (unsigned short*)alloc((size_t)C_ * H_ * 2);        // 4.1 MB
  unsigned short* W_hebf = (unsigned short*)alloc((size_t)A_ * D_ * 2);        // 1.0 MB
  unsigned short* W_sebf = (unsigned short*)alloc((size_t)A_ * H_ * 2);        // 0.5 MB
  unsigned short* u_all  = (unsigned short*)alloc((size_t)B_ * L_ * H_ * 2);   // 2.0 MB
  float* TY    = (float*)alloc((size_t)B_ * L_ * 4 * H_ * 4);                  // 15.7 MB
  float* part  = (float*)alloc((size_t)8 * 5 * 16384 * 4);                     // 2.6 MB
  float* alpha = (float*)alloc((size_t)B_ * T_ * 4);
  float* e     = (float*)alloc((size_t)B_ * T_ * 4);
  float* g     = (float*)alloc((size_t)B_ * D_ * 4);
  float* s0    = (float*)alloc((size_t)B_ * H_ * 4);
  float* s1    = (float*)alloc((size_t)B_ * H_ * 4);
  float* c     = (float*)alloc((size_t)B_ * H_ * 4);
  float* sE    = (float*)alloc((size_t)B_ * A_ * 4);

  // Precompute-only scratch aliases (dead after TY GEMM, stream-ordered):
  unsigned short* targetsbf = hEbf;   // 15.4 MB <= 26.2 MB
  unsigned short* W_ysbf    = hbbf;   // 16.4 MB <= 52.4 MB

  hipMemsetAsync(alpha, 0, (size_t)B_ * T_ * 4, stream);
  hipMemsetAsync(s0, 0, (size_t)B_ * H_ * 4, stream);
  hipMemsetAsync(c, 0, (size_t)B_ * H_ * 4, stream);
  hipMemsetAsync(sE, 0, (size_t)B_ * A_ * 4, stream);

  // ---- precompute ----
  {
    // TY = targets @ W_ys.T  (bf16 MFMA), using scratch aliases
    int n4t = B_ * L_ * C_ / 4;
    k_cvt_f4<<<(n4t + 255) / 256, 256, 0, stream>>>((const float4*)targets,
                                                    (ushort4*)targetsbf, n4t);
    int n4w = 4 * H_ * C_ / 4;
    k_cvt_f4<<<(n4w + 255) / 256, 256, 0, stream>>>((const float4*)W_ys,
                                                    (ushort4*)W_ysbf, n4w);
    gemm_bf16_nt<<<dim3(2048 / 128, 1920 / 128), 256, 0, stream>>>(
        targetsbf, W_ysbf, TY, nullptr, nullptr, 1920, 2048, 4000);

    // hE = hbatch @ W_he.T (bf16 MFMA, bf16 out) — overwrites scratch aliases
    int n4h = B_ * T_ * D_ / 4;
    k_cvt_f4<<<(n4h + 255) / 256, 256, 0, stream>>>((const float4*)hbatch,
                                                    (ushort4*)hbbf, n4h);
    int n4e = A_ * D_ / 4;
    k_cvt_f4<<<(n4e + 255) / 256, 256, 0, stream>>>((const float4*)W_he,
                                                    (ushort4*)W_hebf, n4e);
    gemm_bf16_nt<<<dim3(A_ / 128, (B_ * T_) / 128), 256, 0, stream>>>(
        hbbf, W_hebf, nullptr, hEbf, nullptr, B_ * T_, A_, D_);

    int n4y = C_ * H_ / 4;
    k_cvt_f4<<<(n4y + 255) / 256, 256, 0, stream>>>((const float4*)W_yy,
                                                    (ushort4*)Wyybf, n4y);
    int n4s = A_ * H_ / 4;
    k_cvt_f4<<<(n4s + 255) / 256, 256, 0, stream>>>((const float4*)W_se,
                                                    (ushort4*)W_sebf, n4s);
    int nw = 5 * H_ * KC_;
    k_build_wcell<<<(nw + 255) / 256, 256, 0, stream>>>(W_gy, W_sy, W_gs, W_ss,
                                                        Wcell);
  }

  // ---- 60-step decode loop (4 launches/step) ----
  float* s_in = s0;
  float* s_out = s1;
  for (int l = 0; l < L_; l++) {
    k_att<<<dim3((T_ + TT_ - 1) / TT_, B_), 256, 0, stream>>>(
        alpha, sE, hEbf, conv_w, conv_b, W_fe, w_ee, lengths, e);
    k_softmax_g<<<dim3(8, B_), 256, 0, stream>>>(e, hbbf, lengths, alpha, g);
    k_cell<<<dim3(64, 8), 256, 0, stream>>>(g, s_in, Wcell, part);
    k_fin_se<<<dim3(32), 256, 0, stream>>>(part, c, TY, l, b_gy, b_gs, W_sebf,
                                           u_all, s_out, sE);
    float* tmp = s_in; s_in = s_out; s_out = tmp;
  }

  // ---- final: out[b,l,:] = u_all @ W_yy.T + b_yy  (bf16 MFMA) ----
  gemm_bf16_nt<<<dim3((C_ + 127) / 128, 1920 / 128), 256, 0, stream>>>(
      u_all, Wyybf, out, nullptr, b_yy, 1920, C_, H_);
}